// Round 1
// baseline (1446.971 us; speedup 1.0000x reference)
//
#include <hip/hip_runtime.h>

#define TILE      64
#define NTHREADS  256

__device__ __forceinline__ float silu_f(float x) {
  return x / (1.0f + __expf(-x));
}

// Dense layer tile: 64 edges x OUTW cols, input IND, weight chunked CH rows.
// Thread t -> edge-group et = t>>5 (8 edges), col-group jt = t&31 (4 cols).
template<int IND, int OUTW, int CH>
__device__ __forceinline__ void mm_tile(
    const float* __restrict__ gW, float wscale,
    const float* __restrict__ inb, int stride,
    float* __restrict__ wbuf,
    int tid, float acc[8][4])
{
  const int et = tid >> 5;
  const int jt = tid & 31;
  const int j0 = jt * 4;

#pragma unroll
  for (int e = 0; e < 8; ++e)
#pragma unroll
    for (int c = 0; c < 4; ++c) acc[e][c] = 0.0f;

  for (int r0 = 0; r0 < IND; r0 += CH) {
    __syncthreads();
    {
      const float4* gw4 = (const float4*)(gW + r0 * OUTW);
      float4* wb4 = (float4*)wbuf;
#pragma unroll 1
      for (int idx = tid; idx < CH * OUTW / 4; idx += NTHREADS) {
        float4 v = gw4[idx];
        v.x *= wscale; v.y *= wscale; v.z *= wscale; v.w *= wscale;
        wb4[idx] = v;
      }
    }
    __syncthreads();
    if (j0 < OUTW) {
      const float4* wb4 = (const float4*)wbuf;
#pragma unroll 2
      for (int i0 = 0; i0 < CH; i0 += 4) {
        float4 f[8];
#pragma unroll
        for (int e = 0; e < 8; ++e)
          f[e] = *(const float4*)(inb + (et * 8 + e) * stride + r0 + i0);
        float4 w0 = wb4[(i0 + 0) * (OUTW / 4) + jt];
        float4 w1 = wb4[(i0 + 1) * (OUTW / 4) + jt];
        float4 w2 = wb4[(i0 + 2) * (OUTW / 4) + jt];
        float4 w3 = wb4[(i0 + 3) * (OUTW / 4) + jt];
#pragma unroll
        for (int e = 0; e < 8; ++e) {
          float4 fe = f[e];
          acc[e][0] += fe.x * w0.x + fe.y * w1.x + fe.z * w2.x + fe.w * w3.x;
          acc[e][1] += fe.x * w0.y + fe.y * w1.y + fe.z * w2.y + fe.w * w3.y;
          acc[e][2] += fe.x * w0.z + fe.y * w1.z + fe.z * w2.z + fe.w * w3.z;
          acc[e][3] += fe.x * w0.w + fe.y * w1.w + fe.z * w2.w + fe.w * w3.w;
        }
      }
    }
  }
}

__global__ __launch_bounds__(NTHREADS, 1)
void init_layer_kernel(const int* __restrict__ edge_index,
                       const float* __restrict__ edge_sh,
                       const float* __restrict__ edge_length,
                       const float* __restrict__ edge_one_hot,
                       const float* __restrict__ bessel_w,
                       const float* __restrict__ W1,
                       const float* __restrict__ W2,
                       const float* __restrict__ W3,
                       const float* __restrict__ Wenv,
                       float* __restrict__ out_lat,
                       float* __restrict__ out_node)
{
  __shared__ float feat[TILE][136];   // 34816 B (also reused as ws[64][96])
  __shared__ float actA[TILE][128];   // 32768 B
  __shared__ float wbuf[68 * 128];    // 34816 B
  __shared__ float cutL[TILE];
  __shared__ float shL[TILE][9];
  __shared__ int   nodeL[TILE];

  const int tid = threadIdx.x;
  const int base = blockIdx.x * TILE;
  const int et = tid >> 5;
  const int jt = tid & 31;
  const int j0 = jt * 4;

  // ---- stage per-edge data ----
  if (tid < TILE) {
    float r = edge_length[base + tid];
    float x = r * 0.2f;                       // r / R_MAX
    float x2 = x * x, x3 = x2 * x, x6 = x3 * x3;
    float c = 1.0f - 28.0f * x6 + 48.0f * x6 * x - 21.0f * x6 * x2;
    cutL[tid] = (x < 1.0f) ? c : 0.0f;
    nodeL[tid] = edge_index[base + tid];      // row 0 of (2,E)
    float inv_r = 1.0f / r;
#pragma unroll
    for (int k = 0; k < 8; ++k)
      feat[tid][128 + k] = 0.4f * sinf(bessel_w[k] * x) * inv_r;  // 2/R_MAX = 0.4
  }
  for (int idx = tid; idx < TILE * 9; idx += NTHREADS)
    (&shL[0][0])[idx] = edge_sh[(size_t)base * 9 + idx];
  {
    const float4* oh4 = (const float4*)edge_one_hot + (size_t)base * 32;
    int c = tid & 31, e0 = tid >> 5;
#pragma unroll
    for (int it = 0; it < 8; ++it) {
      int e = e0 + it * 8;
      *(float4*)&feat[e][c * 4] = oh4[e * 32 + c];
    }
  }

  float acc[8][4];

  // layer 1: 136 -> 128, scale 136^-0.5
  mm_tile<136, 128, 68>(W1, 0.08574929257125442f, &feat[0][0], 136, wbuf, tid, acc);
#pragma unroll
  for (int e = 0; e < 8; ++e) {
    float4 v;
    v.x = silu_f(acc[e][0]); v.y = silu_f(acc[e][1]);
    v.z = silu_f(acc[e][2]); v.w = silu_f(acc[e][3]);
    *(float4*)&actA[et * 8 + e][j0] = v;
  }

  // layer 2: 128 -> 128
  mm_tile<128, 128, 64>(W2, 0.08838834764831845f, &actA[0][0], 128, wbuf, tid, acc);
#pragma unroll
  for (int e = 0; e < 8; ++e) {
    float4 v;
    v.x = silu_f(acc[e][0]); v.y = silu_f(acc[e][1]);
    v.z = silu_f(acc[e][2]); v.w = silu_f(acc[e][3]);
    *(float4*)&feat[et * 8 + e][j0] = v;   // reuse feat as act2 (stride 136)
  }

  // layer 3: 128 -> 128, then latents = cutoff * lat
  mm_tile<128, 128, 64>(W3, 0.08838834764831845f, &feat[0][0], 136, wbuf, tid, acc);
#pragma unroll
  for (int e = 0; e < 8; ++e) {
    int ee = et * 8 + e;
    float cut = cutL[ee];
    float4 v;
    v.x = acc[e][0] * cut; v.y = acc[e][1] * cut;
    v.z = acc[e][2] * cut; v.w = acc[e][3] * cut;
    *(float4*)&actA[ee][j0] = v;                                   // latents -> LDS
    ((float4*)out_lat)[(size_t)(base + ee) * 32 + jt] = v;         // latents -> global
  }

  // env layer: 128 -> 96 (weights tile)
  mm_tile<128, 96, 64>(Wenv, 0.08838834764831845f, &actA[0][0], 128, wbuf, tid, acc);
  float* wsL = &feat[0][0];   // reuse feat buffer as ws[64][96]
  if (j0 < 96) {
#pragma unroll
    for (int e = 0; e < 8; ++e) {
      int ee = et * 8 + e;
      float4 v; v.x = acc[e][0]; v.y = acc[e][1]; v.z = acc[e][2]; v.w = acc[e][3];
      *(float4*)&wsL[ee * 96 + j0] = v;
    }
  }
  __syncthreads();

  // scatter: ef[e][k] = ws[e][p*32+m] * sh[e][sidx], atomic into node row
  const float SC = 0.17677669529663687f;   // 32^-0.5
#pragma unroll 1
  for (int k = tid; k < 288; k += NTHREADS) {
    int widx, sidx;
    if (k < 32)       { widx = k;                 sidx = 0; }
    else if (k < 128) { int t = k - 32;  widx = 32 + t / 3; sidx = 1 + t % 3; }
    else              { int t = k - 128; widx = 64 + t / 5; sidx = 4 + t % 5; }
#pragma unroll 1
    for (int e = 0; e < TILE; ++e) {
      float val = wsL[e * 96 + widx] * shL[e][sidx] * SC;
      atomicAdd(out_node + (size_t)nodeL[e] * 288 + k, val);
    }
  }
}

extern "C" void kernel_launch(void* const* d_in, const int* in_sizes, int n_in,
                              void* d_out, int out_size, void* d_ws, size_t ws_size,
                              hipStream_t stream) {
  const int*   edge_index   = (const int*)d_in[0];
  // d_in[1] atom_type, d_in[2] bond_type: unused by reference
  const float* edge_sh      = (const float*)d_in[3];
  const float* edge_length  = (const float*)d_in[4];
  const float* edge_one_hot = (const float*)d_in[5];
  const float* bessel_w     = (const float*)d_in[6];
  const float* W1           = (const float*)d_in[7];
  const float* W2           = (const float*)d_in[8];
  const float* W3           = (const float*)d_in[9];
  const float* Wenv         = (const float*)d_in[10];

  const int E = in_sizes[4];        // 320000
  const int N = in_sizes[1];        // 10000

  float* out_lat  = (float*)d_out;
  float* out_node = out_lat + (size_t)E * 128;

  hipMemsetAsync(out_node, 0, (size_t)N * 288 * sizeof(float), stream);

  init_layer_kernel<<<E / TILE, NTHREADS, 0, stream>>>(
      edge_index, edge_sh, edge_length, edge_one_hot, bessel_w,
      W1, W2, W3, Wenv, out_lat, out_node);
}